// Round 11
// baseline (262.808 us; speedup 1.0000x reference)
//
#include <hip/hip_runtime.h>
#include <hip/hip_bf16.h>
#include <stdint.h>

typedef __bf16 bf16;
typedef __bf16 bf16x8 __attribute__((ext_vector_type(8)));
typedef __bf16 bf16x4 __attribute__((ext_vector_type(4)));
typedef float f32x4 __attribute__((ext_vector_type(4)));

#define N_TOK 4096
#define DDIM 1024
#define HDIM 2048
#define NPAIR 8192

__device__ __forceinline__ void gload16(const void* g, void* l) {
  __builtin_amdgcn_global_load_lds(
      (const __attribute__((address_space(1))) unsigned int*)g,
      (__attribute__((address_space(3))) unsigned int*)l, 16, 0, 0);
}

// ------- per-expert transpose+convert: in [R][C] f32 -> out [C][R] bf16 -------
__global__ void transpose_cvt_kernel(const float* __restrict__ in, bf16* __restrict__ out,
                                     int R, int C) {
  __shared__ float tile[32][33];
  const float* ip = in + (size_t)blockIdx.z * R * C;
  bf16* op = out + (size_t)blockIdx.z * R * C;
  int r0 = blockIdx.y * 32, c0 = blockIdx.x * 32;
  int tr = threadIdx.x >> 3;
  int tc = (threadIdx.x & 7) * 4;
  float4 v = *(const float4*)(ip + (size_t)(r0 + tr) * C + c0 + tc);
  tile[tr][tc] = v.x; tile[tr][tc + 1] = v.y; tile[tr][tc + 2] = v.z; tile[tr][tc + 3] = v.w;
  __syncthreads();
  bf16x4 o = {(bf16)tile[tc + 0][tr], (bf16)tile[tc + 1][tr],
              (bf16)tile[tc + 2][tr], (bf16)tile[tc + 3][tr]};
  *(bf16x4*)(op + (size_t)(c0 + tr) * R + r0 + tc) = o;
}

// -- gating: fp32 logits, softmax, top-2; emits xb; zeroes y2a/y2b partials --
__global__ void gate_kernel(const float* __restrict__ x, const float* __restrict__ Wg,
                            int2* __restrict__ ge, float2* __restrict__ gp,
                            bf16* __restrict__ xb, float* __restrict__ y2a,
                            float* __restrict__ y2b) {
  int t0 = blockIdx.x * 4;
  {
    float4 z = make_float4(0.f, 0.f, 0.f, 0.f);
    float4* za = (float4*)(y2a + (size_t)t0 * DDIM);
    float4* zb = (float4*)(y2b + (size_t)t0 * DDIM);
#pragma unroll
    for (int r = 0; r < 4; r++) {
      za[r * 256 + threadIdx.x] = z;
      zb[r * 256 + threadIdx.x] = z;
    }
  }
  int t = t0 + (threadIdx.x >> 6);
  int lane = threadIdx.x & 63;
  const float* xr = x + (size_t)t * DDIM;
  bf16* xbr = xb + (size_t)t * DDIM;
  float a[8];
#pragma unroll
  for (int e = 0; e < 8; e++) a[e] = 0.f;
#pragma unroll
  for (int it = 0; it < 4; it++) {
    int d0 = it * 256 + lane * 4;
    float4 xv = *(const float4*)(xr + d0);
    bf16x4 o = {(bf16)xv.x, (bf16)xv.y, (bf16)xv.z, (bf16)xv.w};
    *(bf16x4*)(xbr + d0) = o;
    float xs[4] = {xv.x, xv.y, xv.z, xv.w};
#pragma unroll
    for (int dd = 0; dd < 4; dd++) {
      float4 w0 = *(const float4*)(Wg + (size_t)(d0 + dd) * 8);
      float4 w1 = *(const float4*)(Wg + (size_t)(d0 + dd) * 8 + 4);
      a[0] += xs[dd] * w0.x; a[1] += xs[dd] * w0.y; a[2] += xs[dd] * w0.z; a[3] += xs[dd] * w0.w;
      a[4] += xs[dd] * w1.x; a[5] += xs[dd] * w1.y; a[6] += xs[dd] * w1.z; a[7] += xs[dd] * w1.w;
    }
  }
#pragma unroll
  for (int off = 32; off >= 1; off >>= 1) {
#pragma unroll
    for (int e = 0; e < 8; e++) a[e] += __shfl_xor(a[e], off);
  }
  if (lane == 0) {
    float m = a[0];
#pragma unroll
    for (int e = 1; e < 8; e++) m = fmaxf(m, a[e]);
    float p[8]; float s = 0.f;
#pragma unroll
    for (int e = 0; e < 8; e++) { p[e] = expf(a[e] - m); s += p[e]; }
    float inv = 1.f / s;
    int i0 = 0; float v0 = a[0];
#pragma unroll
    for (int e = 1; e < 8; e++) if (a[e] > v0) { v0 = a[e]; i0 = e; }
    int i1 = -1; float v1 = -1e30f;
#pragma unroll
    for (int e = 0; e < 8; e++) if (e != i0 && a[e] > v1) { v1 = a[e]; i1 = e; }
    ge[t] = make_int2(i0, i1);
    gp[t] = make_float2(p[i0] * inv, p[i1] * inv);
  }
}

// ------- deterministic stable counting sort of 8192 pairs by expert (1 block) -------
// meta[0..8]=segment base; meta[9..16]=tileStart (BM=256), meta[17]=totalTiles
__global__ void sort_kernel(const int2* __restrict__ ge, const float2* __restrict__ gp,
                            int* __restrict__ tok, float* __restrict__ ps,
                            int* __restrict__ meta) {
  __shared__ int hist[8], runn[8], wc[16][8], wb[16][8], baseS[9];
  int tid = threadIdx.x;
  int lane = tid & 63, wv = tid >> 6;
  if (tid < 8) hist[tid] = 0;
  __syncthreads();
  for (int i = tid; i < NPAIR; i += 1024) {
    int2 g = ge[i >> 1];
    int e = (i & 1) ? g.y : g.x;
    atomicAdd(&hist[e], 1);
  }
  __syncthreads();
  if (tid == 0) {
    int b = 0, ts = 0;
    for (int e = 0; e < 8; e++) {
      baseS[e] = b; meta[e] = b;
      meta[9 + e] = ts; ts += (hist[e] + 255) / 256;
      b += hist[e];
    }
    baseS[8] = b; meta[8] = b; meta[17] = ts;
  }
  __syncthreads();
  if (tid < 8) runn[tid] = baseS[tid];
  __syncthreads();
  for (int c = 0; c < 8; c++) {
    int i = c * 1024 + tid;
    int2 g = ge[i >> 1];
    int e = (i & 1) ? g.y : g.x;
    int rank = 0;
#pragma unroll
    for (int ee = 0; ee < 8; ee++) {
      unsigned long long b = __ballot(e == ee);
      if (e == ee) rank = __popcll(b & ((1ull << lane) - 1ull));
      if (lane == 0) wc[wv][ee] = __popcll(b);
    }
    __syncthreads();
    if (tid < 8) {
      int s = runn[tid];
      for (int w = 0; w < 16; w++) { wb[w][tid] = s; s += wc[w][tid]; }
      runn[tid] = s;
    }
    __syncthreads();
    int pos = wb[wv][e] + rank;
    tok[pos] = i >> 1;
    float2 p2 = gp[i >> 1];
    ps[pos] = (i & 1) ? p2.y : p2.x;
    __syncthreads();
  }
}

// ---- grouped GEMM: 256x256 tile, BK=32, 512 thr = 8 waves (2M x 4N) ----
// R11: arithmetic-intensity attack. Per K-tile: 256 MFMA (1242 cyc of CU matrix
// pipe) vs 32 KB staged (~600-900 cyc) -> MFMA is the long pole (128 B/MFMA vs
// 256 at 128-sq). 3-slot ring (32 KiB/slot = 96 KiB), 1 block/CU, per-iter:
//   vmcnt(4)+barrier   [confirms tile j (staged 2 iters ago); j+1 in flight]
//   stage(j+2)         [post-barrier: slot j-1 safe -- every wave's j-1 reads
//                       were lgkm-drained by its MFMAs before the barrier]
//   12x ds_read_b128 (tile j) ; 32 MFMA/wave (compiler-interleaved lgkm)
// T2 16B-chunk swizzle via pre-swizzled source; T5 setprio; XCD-chunked map.
// FIRST: A=xb[tok[row]] (K=1024), B=W1T -> hout = relu(A*B + b1), bf16
// !FIRST: A=hbuf, K=2048 split-K2 via tileN>>2; atomicAdd into y2a/y2b.
template <bool FIRST>
__global__ __launch_bounds__(512, 1)
void moe_gemm_kernel(const bf16* __restrict__ A, const bf16* __restrict__ Bt,
                     const float* __restrict__ bias, const int* __restrict__ tok,
                     const float* __restrict__ ps, const int* __restrict__ meta,
                     bf16* __restrict__ hout, float* __restrict__ y2a,
                     float* __restrict__ y2b) {
  constexpr int AK  = FIRST ? DDIM : HDIM;  // A/B row stride (K dim of full op)
  constexpr int NPE = FIRST ? HDIM : DDIM;  // B rows per expert (= N)
  constexpr int NT  = 8;                    // FIRST: 8 n-tiles; else 4 n x 2 k
  constexpr int nk  = 32;                   // K = 1024 per (half-)dispatch
  __shared__ bf16 lds[3][16384];            // slot: A 256x32 | B 256x32

  int MTa = meta[17];
  int xcd = blockIdx.x & 7;
  int idx = blockIdx.x >> 3;
  int mLo = (MTa * xcd) >> 3;
  int mHi = (MTa * (xcd + 1)) >> 3;
  int cnt = mHi - mLo;
  if (idx >= cnt * NT) return;
  int tileN = idx / cnt;
  int tileM = mLo + idx - tileN * cnt;

  int e = 0;
#pragma unroll
  for (int k = 1; k < 8; k++) if (tileM >= meta[9 + k]) e = k;
  int row0 = meta[e] + (tileM - meta[9 + e]) * 256;
  int segEnd = meta[e + 1];
  int n0, kOff;
  if (FIRST) { n0 = tileN * 256; kOff = 0; }
  else       { n0 = (tileN & 3) * 256; kOff = (tileN >> 2) * 1024; }

  int t = threadIdx.x;
  // staging: unit u -> rows u*128 + (t>>2), dest 16B-chunk t&3 (linear dest);
  // pre-swizzle SOURCE chunk: c' = (t&3) ^ ((row>>1)&3) = (t&3) ^ ((t>>3)&3)
  int swz = ((t & 3) ^ ((t >> 3) & 3)) * 8;
  const bf16* aSrc[2];
  const bf16* bSrc[2];
#pragma unroll
  for (int u = 0; u < 2; u++) {
    int row = u * 128 + (t >> 2);
    int gRow = row0 + row; if (gRow > NPAIR - 1) gRow = NPAIR - 1;
    int arow = FIRST ? tok[gRow] : gRow;
    aSrc[u] = A + (size_t)arow * AK + kOff + swz;
    bSrc[u] = Bt + ((size_t)e * NPE + n0 + row) * AK + kOff + swz;
  }

  int lane = t & 63, wv = t >> 6;
  int wm = wv >> 2, wn = wv & 3;  // 2M x 4N waves; per-wave out 128x64
  int l15 = lane & 15, l4 = lane >> 4;
  int aOff[8], bOff[4];
#pragma unroll
  for (int mf = 0; mf < 8; mf++) {
    int row = wm * 128 + mf * 16 + l15;
    aOff[mf] = row * 32 + ((l4 ^ ((row >> 1) & 3)) * 8);
  }
#pragma unroll
  for (int nf = 0; nf < 4; nf++) {
    int row = wn * 64 + nf * 16 + l15;
    bOff[nf] = 8192 + row * 32 + ((l4 ^ ((row >> 1) & 3)) * 8);
  }

  f32x4 acc[8][4];
#pragma unroll
  for (int mf = 0; mf < 8; mf++)
#pragma unroll
    for (int nf = 0; nf < 4; nf++)
#pragma unroll
      for (int j = 0; j < 4; j++) acc[mf][nf][j] = 0.f;

  auto STAGE = [&](int j) {
    bf16* sb = &lds[j % 3][0];
    gload16(aSrc[0] + j * 32, sb + t * 8);
    gload16(aSrc[1] + j * 32, sb + 4096 + t * 8);
    gload16(bSrc[0] + j * 32, sb + 8192 + t * 8);
    gload16(bSrc[1] + j * 32, sb + 12288 + t * 8);
  };

  // prologue: tiles 0 and 1 in flight (8 loads/thread)
  STAGE(0);
  STAGE(1);

  for (int j = 0; j < nk; j++) {
    // confirm tile j: outstanding = j+1's 4 (newest); all older (= tile j) drain.
    if (j + 1 < nk) asm volatile("s_waitcnt vmcnt(4)\n\ts_barrier" ::: "memory");
    else            asm volatile("s_waitcnt vmcnt(0)\n\ts_barrier" ::: "memory");
    // post-barrier stage into slot (j+2)%3 == (j-1)%3: safe, every wave's tile
    // j-1 frag-reads completed before it entered this barrier.
    if (j + 2 < nk) STAGE(j + 2);
    const bf16* sb = &lds[j % 3][0];
    bf16x8 af[8], bfr[4];
#pragma unroll
    for (int mf = 0; mf < 8; mf++) af[mf] = *(const bf16x8*)(sb + aOff[mf]);
#pragma unroll
    for (int nf = 0; nf < 4; nf++) bfr[nf] = *(const bf16x8*)(sb + bOff[nf]);
    __builtin_amdgcn_s_setprio(1);
#pragma unroll
    for (int mf = 0; mf < 8; mf++)
#pragma unroll
      for (int nf = 0; nf < 4; nf++)
        acc[mf][nf] = __builtin_amdgcn_mfma_f32_16x16x32_bf16(af[mf], bfr[nf], acc[mf][nf], 0, 0, 0);
    __builtin_amdgcn_s_setprio(0);
  }

  // epilogue
  int colb = n0 + wn * 64 + l15;
  float bia[4];
#pragma unroll
  for (int nf = 0; nf < 4; nf++)
    bia[nf] = (FIRST || kOff == 0) ? bias[(size_t)e * NPE + colb + nf * 16] : 0.f;
  float* ybuf = FIRST ? nullptr : ((kOff == 0) ? y2a : y2b);
#pragma unroll
  for (int mf = 0; mf < 8; mf++) {
#pragma unroll
    for (int jj = 0; jj < 4; jj++) {
      int gRow = row0 + wm * 128 + mf * 16 + l4 * 4 + jj;
      if (gRow < segEnd) {
        if (FIRST) {
#pragma unroll
          for (int nf = 0; nf < 4; nf++) {
            float v = acc[mf][nf][jj] + bia[nf];
            hout[(size_t)gRow * HDIM + colb + nf * 16] = (bf16)fmaxf(v, 0.f);
          }
        } else {
          float pscale = ps[gRow];
          float* orow = ybuf + (size_t)tok[gRow] * DDIM;
#pragma unroll
          for (int nf = 0; nf < 4; nf++)
            atomicAdd(orow + colb + nf * 16, (acc[mf][nf][jj] + bia[nf]) * pscale);
        }
      }
    }
  }
}

// ---------------- combine: out = y2a + y2b ----------------
__global__ void combine_kernel(const float* __restrict__ a, const float* __restrict__ b,
                               float* __restrict__ out) {
  int i = blockIdx.x * 256 + threadIdx.x;
  f32x4 va = ((const f32x4*)a)[i];
  f32x4 vb = ((const f32x4*)b)[i];
  ((f32x4*)out)[i] = va + vb;
}

extern "C" void kernel_launch(void* const* d_in, const int* in_sizes, int n_in,
                              void* d_out, int out_size, void* d_ws, size_t ws_size,
                              hipStream_t stream) {
  (void)in_sizes; (void)n_in; (void)out_size; (void)ws_size;
  const float* x  = (const float*)d_in[0];
  const float* Wg = (const float*)d_in[1];
  const float* W1 = (const float*)d_in[2];
  const float* b1 = (const float*)d_in[3];
  const float* W2 = (const float*)d_in[4];
  const float* b2 = (const float*)d_in[5];
  float* out = (float*)d_out;

  char* ws = (char*)d_ws;
  bf16*  xb   = (bf16*)(ws);                     //   8 MiB: [4096][1024] bf16
  bf16*  W1T  = (bf16*)(ws + (8ull  << 20));     //  32 MiB: [8][2048][1024] bf16
  bf16*  W2T  = (bf16*)(ws + (40ull << 20));     //  32 MiB: [8][1024][2048] bf16
  bf16*  hbuf = (bf16*)(ws + (72ull << 20));     //  32 MiB: [8192][2048] bf16
  float* y2a  = (float*)(ws + (104ull << 20));   //  16 MiB: [4096][1024] f32
  float* y2b  = (float*)(ws + (120ull << 20));   //  16 MiB: [4096][1024] f32
  char*  ext  = ws + (136ull << 20);
  int2*   ge      = (int2*)(ext);
  float2* gp      = (float2*)(ext + (64u  << 10));
  int*    tok     = (int*)(ext + (128u << 10));
  float*  psarr   = (float*)(ext + (160u << 10));
  int*    meta    = (int*)(ext + (224u << 10));

  transpose_cvt_kernel<<<dim3(64, 32, 8), 256, 0, stream>>>(W1, W1T, 1024, 2048);
  transpose_cvt_kernel<<<dim3(32, 64, 8), 256, 0, stream>>>(W2, W2T, 2048, 1024);
  gate_kernel<<<1024, 256, 0, stream>>>(x, Wg, ge, gp, xb, y2a, y2b);
  sort_kernel<<<1, 1024, 0, stream>>>(ge, gp, tok, psarr, meta);
  // per-XCD M-slots = ceil(39/8) = 5; grid = 5 * NT(8) * 8 XCD = 320 both
  moe_gemm_kernel<true><<<dim3(320), 512, 0, stream>>>(
      xb, W1T, b1, tok, psarr, meta, hbuf, nullptr, nullptr);
  moe_gemm_kernel<false><<<dim3(320), 512, 0, stream>>>(
      hbuf, W2T, b2, tok, psarr, meta, nullptr, y2a, y2b);
  combine_kernel<<<4096, 256, 0, stream>>>(y2a, y2b, out);
}

// Round 12
// 253.467 us; speedup vs baseline: 1.0369x; 1.0369x over previous
//
#include <hip/hip_runtime.h>
#include <hip/hip_bf16.h>
#include <stdint.h>

typedef __bf16 bf16;
typedef __bf16 bf16x8 __attribute__((ext_vector_type(8)));
typedef __bf16 bf16x4 __attribute__((ext_vector_type(4)));
typedef float f32x4 __attribute__((ext_vector_type(4)));

#define N_TOK 4096
#define DDIM 1024
#define HDIM 2048
#define NPAIR 8192

__device__ __forceinline__ void gload16(const void* g, void* l) {
  __builtin_amdgcn_global_load_lds(
      (const __attribute__((address_space(1))) unsigned int*)g,
      (__attribute__((address_space(3))) unsigned int*)l, 16, 0, 0);
}

// ------- per-expert transpose+convert: in [R][C] f32 -> out [C][R] bf16 -------
__global__ void transpose_cvt_kernel(const float* __restrict__ in, bf16* __restrict__ out,
                                     int R, int C) {
  __shared__ float tile[32][33];
  const float* ip = in + (size_t)blockIdx.z * R * C;
  bf16* op = out + (size_t)blockIdx.z * R * C;
  int r0 = blockIdx.y * 32, c0 = blockIdx.x * 32;
  int tr = threadIdx.x >> 3;
  int tc = (threadIdx.x & 7) * 4;
  float4 v = *(const float4*)(ip + (size_t)(r0 + tr) * C + c0 + tc);
  tile[tr][tc] = v.x; tile[tr][tc + 1] = v.y; tile[tr][tc + 2] = v.z; tile[tr][tc + 3] = v.w;
  __syncthreads();
  bf16x4 o = {(bf16)tile[tc + 0][tr], (bf16)tile[tc + 1][tr],
              (bf16)tile[tc + 2][tr], (bf16)tile[tc + 3][tr]};
  *(bf16x4*)(op + (size_t)(c0 + tr) * R + r0 + tc) = o;
}

// -- gating: fp32 logits, softmax, top-2; emits xb (bf16 x) and zeroes out rows --
__global__ void gate_kernel(const float* __restrict__ x, const float* __restrict__ Wg,
                            int2* __restrict__ ge, float2* __restrict__ gp,
                            bf16* __restrict__ xb, float* __restrict__ outp) {
  int t0 = blockIdx.x * 4;
  {
    float4 z = make_float4(0.f, 0.f, 0.f, 0.f);
    float4* ob = (float4*)(outp + (size_t)t0 * DDIM);
#pragma unroll
    for (int r = 0; r < 4; r++) ob[r * 256 + threadIdx.x] = z;
  }
  int t = t0 + (threadIdx.x >> 6);
  int lane = threadIdx.x & 63;
  const float* xr = x + (size_t)t * DDIM;
  bf16* xbr = xb + (size_t)t * DDIM;
  float a[8];
#pragma unroll
  for (int e = 0; e < 8; e++) a[e] = 0.f;
#pragma unroll
  for (int it = 0; it < 4; it++) {
    int d0 = it * 256 + lane * 4;
    float4 xv = *(const float4*)(xr + d0);
    bf16x4 o = {(bf16)xv.x, (bf16)xv.y, (bf16)xv.z, (bf16)xv.w};
    *(bf16x4*)(xbr + d0) = o;
    float xs[4] = {xv.x, xv.y, xv.z, xv.w};
#pragma unroll
    for (int dd = 0; dd < 4; dd++) {
      float4 w0 = *(const float4*)(Wg + (size_t)(d0 + dd) * 8);
      float4 w1 = *(const float4*)(Wg + (size_t)(d0 + dd) * 8 + 4);
      a[0] += xs[dd] * w0.x; a[1] += xs[dd] * w0.y; a[2] += xs[dd] * w0.z; a[3] += xs[dd] * w0.w;
      a[4] += xs[dd] * w1.x; a[5] += xs[dd] * w1.y; a[6] += xs[dd] * w1.z; a[7] += xs[dd] * w1.w;
    }
  }
#pragma unroll
  for (int off = 32; off >= 1; off >>= 1) {
#pragma unroll
    for (int e = 0; e < 8; e++) a[e] += __shfl_xor(a[e], off);
  }
  if (lane == 0) {
    float m = a[0];
#pragma unroll
    for (int e = 1; e < 8; e++) m = fmaxf(m, a[e]);
    float p[8]; float s = 0.f;
#pragma unroll
    for (int e = 0; e < 8; e++) { p[e] = expf(a[e] - m); s += p[e]; }
    float inv = 1.f / s;
    int i0 = 0; float v0 = a[0];
#pragma unroll
    for (int e = 1; e < 8; e++) if (a[e] > v0) { v0 = a[e]; i0 = e; }
    int i1 = -1; float v1 = -1e30f;
#pragma unroll
    for (int e = 0; e < 8; e++) if (e != i0 && a[e] > v1) { v1 = a[e]; i1 = e; }
    ge[t] = make_int2(i0, i1);
    gp[t] = make_float2(p[i0] * inv, p[i1] * inv);
  }
}

// ------- deterministic stable counting sort of 8192 pairs by expert (1 block) -------
// meta[0..8]=segment base; meta[9..16]=tileStart (BM=128), meta[17]=total128
__global__ void sort_kernel(const int2* __restrict__ ge, const float2* __restrict__ gp,
                            int* __restrict__ tok, float* __restrict__ ps,
                            int* __restrict__ meta) {
  __shared__ int hist[8], runn[8], wc[16][8], wb[16][8], baseS[9];
  int tid = threadIdx.x;
  int lane = tid & 63, wv = tid >> 6;
  if (tid < 8) hist[tid] = 0;
  __syncthreads();
  for (int i = tid; i < NPAIR; i += 1024) {
    int2 g = ge[i >> 1];
    int e = (i & 1) ? g.y : g.x;
    atomicAdd(&hist[e], 1);
  }
  __syncthreads();
  if (tid == 0) {
    int b = 0, ts1 = 0;
    for (int e = 0; e < 8; e++) {
      baseS[e] = b; meta[e] = b;
      meta[9 + e] = ts1;  ts1 += (hist[e] + 127) / 128;
      b += hist[e];
    }
    baseS[8] = b; meta[8] = b; meta[17] = ts1;
  }
  __syncthreads();
  if (tid < 8) runn[tid] = baseS[tid];
  __syncthreads();
  for (int c = 0; c < 8; c++) {
    int i = c * 1024 + tid;
    int2 g = ge[i >> 1];
    int e = (i & 1) ? g.y : g.x;
    int rank = 0;
#pragma unroll
    for (int ee = 0; ee < 8; ee++) {
      unsigned long long b = __ballot(e == ee);
      if (e == ee) rank = __popcll(b & ((1ull << lane) - 1ull));
      if (lane == 0) wc[wv][ee] = __popcll(b);
    }
    __syncthreads();
    if (tid < 8) {
      int s = runn[tid];
      for (int w = 0; w < 16; w++) { wb[w][tid] = s; s += wc[w][tid]; }
      runn[tid] = s;
    }
    __syncthreads();
    int pos = wb[wv][e] + rank;
    tok[pos] = i >> 1;
    float2 p2 = gp[i >> 1];
    ps[pos] = (i & 1) ? p2.y : p2.x;
    __syncthreads();
  }
}

// ---- grouped GEMM: BM=128, BN=128, BK=32, 256 thr (4 waves 2x2), 3 blocks/CU ----
// VAR=0: real R9 kernel (confirm-distance-1).
// VAR=1: ABLATION no-stage  (no gload_lds/vmcnt; barriers+ds_read+lgkm+MFMA kept)
// VAR=3: ABLATION mfma-only (no gload_lds, no ds_read; constant frags; barriers kept)
template <int KDIM, int NPE, bool FIRST, int NT, int VAR>
__global__ __launch_bounds__(256, 3)
void moe_gemm_kernel(const bf16* __restrict__ A, const bf16* __restrict__ Bt,
                     const float* __restrict__ bias, const int* __restrict__ tok,
                     const float* __restrict__ ps, const int* __restrict__ meta,
                     bf16* __restrict__ hout, float* __restrict__ outp) {
  __shared__ bf16 lds[3][8192];
  constexpr int nk = KDIM / 32;

  int MTa = meta[17];
  int xcd = blockIdx.x & 7;
  int idx = blockIdx.x >> 3;
  int mLo = (MTa * xcd) >> 3;
  int mHi = (MTa * (xcd + 1)) >> 3;
  int cnt = mHi - mLo;
  if (idx >= cnt * NT) return;
  int tileN = idx / cnt;
  int tileM = mLo + idx - tileN * cnt;

  int e = 0;
#pragma unroll
  for (int k = 1; k < 8; k++) if (tileM >= meta[9 + k]) e = k;
  int row0 = meta[e] + (tileM - meta[9 + e]) * 128;
  int segEnd = meta[e + 1];
  int n0 = tileN * 128;

  int t = threadIdx.x;
  const bf16* aSrc[2];
  const bf16* bSrc[2];
  {
    int swz = ((t & 3) ^ ((t >> 3) & 3)) * 8;
#pragma unroll
    for (int r = 0; r < 2; r++) {
      int row = r * 64 + (t >> 2);
      int gRow = row0 + row; if (gRow > NPAIR - 1) gRow = NPAIR - 1;
      int arow = FIRST ? tok[gRow] : gRow;
      aSrc[r] = A + (size_t)arow * KDIM + swz;
      bSrc[r] = Bt + ((size_t)e * NPE + n0 + row) * KDIM + swz;
    }
  }

  int lane = t & 63, wv = t >> 6;
  int wm = wv >> 1, wn = wv & 1;
  int l15 = lane & 15, l4 = lane >> 4;
  int aOff[4], bOff[4];
#pragma unroll
  for (int m = 0; m < 4; m++) {
    int row = wm * 64 + m * 16 + l15;
    aOff[m] = row * 32 + ((l4 ^ ((row >> 1) & 3)) * 8);
  }
#pragma unroll
  for (int n = 0; n < 4; n++) {
    int row = wn * 64 + n * 16 + l15;
    bOff[n] = 4096 + row * 32 + ((l4 ^ ((row >> 1) & 3)) * 8);
  }

  f32x4 acc[4][4];
#pragma unroll
  for (int m = 0; m < 4; m++)
#pragma unroll
    for (int n = 0; n < 4; n++)
#pragma unroll
      for (int j = 0; j < 4; j++) acc[m][n][j] = 0.f;

  auto SA = [&](int j) {
    bf16* sb = &lds[j % 3][0];
    gload16(aSrc[0] + j * 32, sb + t * 8);
    gload16(aSrc[1] + j * 32, sb + 2048 + t * 8);
  };
  auto SB = [&](int j) {
    bf16* sb = &lds[j % 3][0];
    gload16(bSrc[0] + j * 32, sb + 4096 + t * 8);
    gload16(bSrc[1] + j * 32, sb + 6144 + t * 8);
  };

  // constant frags for VAR==3 (runtime-derived; cannot const-fold)
  bf16x8 zf;
#pragma unroll
  for (int q = 0; q < 8; q++) ((bf16*)&zf)[q] = (bf16)(float)((lane + q) & 7);

  // prologue
  if constexpr (VAR == 0) {
    SA(0); SB(0); SA(1); SB(1);
    asm volatile("s_waitcnt vmcnt(4)\n\ts_barrier" ::: "memory");
  } else {
    __builtin_amdgcn_s_barrier();
  }

  for (int j = 0; j < nk; j++) {
    const bf16* sb = &lds[j % 3][0];
    bf16x8 af[4], bfr[4];
    // ---- phase A: m-half 0 ----
    if constexpr (VAR != 3) {
      af[0] = *(const bf16x8*)(sb + aOff[0]);
      af[1] = *(const bf16x8*)(sb + aOff[1]);
#pragma unroll
      for (int n = 0; n < 4; n++) bfr[n] = *(const bf16x8*)(sb + bOff[n]);
    } else {
      af[0] = zf; af[1] = zf; af[2] = zf; af[3] = zf;
#pragma unroll
      for (int n = 0; n < 4; n++) bfr[n] = zf;
    }
    if constexpr (VAR == 0) { if (j + 2 < nk) SA(j + 2); }
    if constexpr (VAR != 3) {
      asm volatile("s_waitcnt lgkmcnt(0)" ::: "memory");
      __builtin_amdgcn_sched_barrier(0);
    }
    __builtin_amdgcn_s_setprio(1);
#pragma unroll
    for (int n = 0; n < 4; n++) {
      acc[0][n] = __builtin_amdgcn_mfma_f32_16x16x32_bf16(af[0], bfr[n], acc[0][n], 0, 0, 0);
      acc[1][n] = __builtin_amdgcn_mfma_f32_16x16x32_bf16(af[1], bfr[n], acc[1][n], 0, 0, 0);
    }
    __builtin_amdgcn_s_setprio(0);
    // ---- phase B: m-half 1 ----
    if constexpr (VAR != 3) {
      af[2] = *(const bf16x8*)(sb + aOff[2]);
      af[3] = *(const bf16x8*)(sb + aOff[3]);
    }
    if constexpr (VAR == 0) { if (j + 2 < nk) SB(j + 2); }
    if constexpr (VAR != 3) {
      asm volatile("s_waitcnt lgkmcnt(0)" ::: "memory");
      __builtin_amdgcn_sched_barrier(0);
    }
    __builtin_amdgcn_s_setprio(1);
#pragma unroll
    for (int n = 0; n < 4; n++) {
      acc[2][n] = __builtin_amdgcn_mfma_f32_16x16x32_bf16(af[2], bfr[n], acc[2][n], 0, 0, 0);
      acc[3][n] = __builtin_amdgcn_mfma_f32_16x16x32_bf16(af[3], bfr[n], acc[3][n], 0, 0, 0);
    }
    __builtin_amdgcn_s_setprio(0);
    // ---- close K-tile ----
    if constexpr (VAR == 0) {
      if (j + 2 < nk)      asm volatile("s_waitcnt vmcnt(4)\n\ts_barrier" ::: "memory");
      else if (j + 1 < nk) asm volatile("s_waitcnt vmcnt(0)\n\ts_barrier" ::: "memory");
    } else {
      if (j + 1 < nk) __builtin_amdgcn_s_barrier();
    }
  }

  int colb = n0 + wn * 64 + l15;
  int rowb = wm * 64 + l4 * 4;
  float bia[4];
#pragma unroll
  for (int n = 0; n < 4; n++) bia[n] = bias[(size_t)e * NPE + colb + n * 16];
#pragma unroll
  for (int m = 0; m < 4; m++) {
#pragma unroll
    for (int jj = 0; jj < 4; jj++) {
      int gRow = row0 + rowb + m * 16 + jj;
      if (gRow < segEnd) {
        if (FIRST) {
#pragma unroll
          for (int n = 0; n < 4; n++) {
            float v = acc[m][n][jj] + bia[n];
            v = fmaxf(v, 0.f);
            hout[(size_t)gRow * NPE + colb + n * 16] = (bf16)v;
          }
        } else {
          float pscale = ps[gRow];
          float* orow = outp + (size_t)tok[gRow] * DDIM;
#pragma unroll
          for (int n = 0; n < 4; n++) {
            float v = (acc[m][n][jj] + bia[n]) * pscale;
            atomicAdd(orow + colb + n * 16, v);
          }
        }
      }
    }
  }
}

extern "C" void kernel_launch(void* const* d_in, const int* in_sizes, int n_in,
                              void* d_out, int out_size, void* d_ws, size_t ws_size,
                              hipStream_t stream) {
  (void)in_sizes; (void)n_in; (void)out_size; (void)ws_size;
  const float* x  = (const float*)d_in[0];
  const float* Wg = (const float*)d_in[1];
  const float* W1 = (const float*)d_in[2];
  const float* b1 = (const float*)d_in[3];
  const float* W2 = (const float*)d_in[4];
  const float* b2 = (const float*)d_in[5];
  float* out = (float*)d_out;

  char* ws = (char*)d_ws;
  bf16*  xb   = (bf16*)(ws);                     //   8 MiB: [4096][1024] bf16
  bf16*  W1T  = (bf16*)(ws + (8ull  << 20));     //  32 MiB: [8][2048][1024] bf16
  bf16*  W2T  = (bf16*)(ws + (40ull << 20));     //  32 MiB: [8][1024][2048] bf16
  bf16*  hbuf = (bf16*)(ws + (72ull << 20));     //  32 MiB: [8192][2048] bf16
  char*  ext  = ws + (104ull << 20);
  int2*   ge      = (int2*)(ext);
  float2* gp      = (float2*)(ext + (64u  << 10));
  int*    tok     = (int*)(ext + (128u << 10));
  float*  psarr   = (float*)(ext + (160u << 10));
  int*    meta    = (int*)(ext + (224u << 10));

  transpose_cvt_kernel<<<dim3(64, 32, 8), 256, 0, stream>>>(W1, W1T, 1024, 2048);
  transpose_cvt_kernel<<<dim3(32, 64, 8), 256, 0, stream>>>(W2, W2T, 2048, 1024);
  gate_kernel<<<1024, 256, 0, stream>>>(x, Wg, ge, gp, xb, out);
  sort_kernel<<<1, 1024, 0, stream>>>(ge, gp, tok, psarr, meta);
  // ---- real pipeline (identical to R9) ----
  moe_gemm_kernel<1024, 2048, true, 16, 0><<<dim3(1152), 256, 0, stream>>>(
      xb, W1T, b1, tok, psarr, meta, hbuf, nullptr);
  moe_gemm_kernel<2048, 1024, false, 8, 0><<<dim3(576), 256, 0, stream>>>(
      hbuf, W2T, b2, tok, psarr, meta, nullptr, out);
  // ---- ablation dispatches (G1-shaped, dump into hbuf AFTER G2 consumed it;
  //      output rows are store-guarded so d_out stays deterministic) ----
  moe_gemm_kernel<1024, 2048, true, 16, 1><<<dim3(1152), 256, 0, stream>>>(
      xb, W1T, b1, tok, psarr, meta, hbuf, nullptr);   // V1: no-stage
  moe_gemm_kernel<1024, 2048, true, 16, 3><<<dim3(1152), 256, 0, stream>>>(
      xb, W1T, b1, tok, psarr, meta, hbuf, nullptr);   // V3: mfma-only
}

// Round 13
// 194.468 us; speedup vs baseline: 1.3514x; 1.3034x over previous
//
#include <hip/hip_runtime.h>
#include <hip/hip_bf16.h>
#include <stdint.h>

typedef __bf16 bf16;
typedef __bf16 bf16x8 __attribute__((ext_vector_type(8)));
typedef __bf16 bf16x4 __attribute__((ext_vector_type(4)));
typedef float f32x4 __attribute__((ext_vector_type(4)));

#define N_TOK 4096
#define DDIM 1024
#define HDIM 2048
#define NPAIR 8192

__device__ __forceinline__ void gload16(const void* g, void* l) {
  __builtin_amdgcn_global_load_lds(
      (const __attribute__((address_space(1))) unsigned int*)g,
      (__attribute__((address_space(3))) unsigned int*)l, 16, 0, 0);
}

// ------- per-expert transpose+convert: in [R][C] f32 -> out [C][R] bf16 -------
__global__ void transpose_cvt_kernel(const float* __restrict__ in, bf16* __restrict__ out,
                                     int R, int C) {
  __shared__ float tile[32][33];
  const float* ip = in + (size_t)blockIdx.z * R * C;
  bf16* op = out + (size_t)blockIdx.z * R * C;
  int r0 = blockIdx.y * 32, c0 = blockIdx.x * 32;
  int tr = threadIdx.x >> 3;
  int tc = (threadIdx.x & 7) * 4;
  float4 v = *(const float4*)(ip + (size_t)(r0 + tr) * C + c0 + tc);
  tile[tr][tc] = v.x; tile[tr][tc + 1] = v.y; tile[tr][tc + 2] = v.z; tile[tr][tc + 3] = v.w;
  __syncthreads();
  bf16x4 o = {(bf16)tile[tc + 0][tr], (bf16)tile[tc + 1][tr],
              (bf16)tile[tc + 2][tr], (bf16)tile[tc + 3][tr]};
  *(bf16x4*)(op + (size_t)(c0 + tr) * R + r0 + tc) = o;
}

// -- gating: fp32 logits, softmax, top-2; emits xb (bf16 x) and zeroes out rows --
__global__ void gate_kernel(const float* __restrict__ x, const float* __restrict__ Wg,
                            int2* __restrict__ ge, float2* __restrict__ gp,
                            bf16* __restrict__ xb, float* __restrict__ outp) {
  int t0 = blockIdx.x * 4;
  {
    float4 z = make_float4(0.f, 0.f, 0.f, 0.f);
    float4* ob = (float4*)(outp + (size_t)t0 * DDIM);
#pragma unroll
    for (int r = 0; r < 4; r++) ob[r * 256 + threadIdx.x] = z;
  }
  int t = t0 + (threadIdx.x >> 6);
  int lane = threadIdx.x & 63;
  const float* xr = x + (size_t)t * DDIM;
  bf16* xbr = xb + (size_t)t * DDIM;
  float a[8];
#pragma unroll
  for (int e = 0; e < 8; e++) a[e] = 0.f;
#pragma unroll
  for (int it = 0; it < 4; it++) {
    int d0 = it * 256 + lane * 4;
    float4 xv = *(const float4*)(xr + d0);
    bf16x4 o = {(bf16)xv.x, (bf16)xv.y, (bf16)xv.z, (bf16)xv.w};
    *(bf16x4*)(xbr + d0) = o;
    float xs[4] = {xv.x, xv.y, xv.z, xv.w};
#pragma unroll
    for (int dd = 0; dd < 4; dd++) {
      float4 w0 = *(const float4*)(Wg + (size_t)(d0 + dd) * 8);
      float4 w1 = *(const float4*)(Wg + (size_t)(d0 + dd) * 8 + 4);
      a[0] += xs[dd] * w0.x; a[1] += xs[dd] * w0.y; a[2] += xs[dd] * w0.z; a[3] += xs[dd] * w0.w;
      a[4] += xs[dd] * w1.x; a[5] += xs[dd] * w1.y; a[6] += xs[dd] * w1.z; a[7] += xs[dd] * w1.w;
    }
  }
#pragma unroll
  for (int off = 32; off >= 1; off >>= 1) {
#pragma unroll
    for (int e = 0; e < 8; e++) a[e] += __shfl_xor(a[e], off);
  }
  if (lane == 0) {
    float m = a[0];
#pragma unroll
    for (int e = 1; e < 8; e++) m = fmaxf(m, a[e]);
    float p[8]; float s = 0.f;
#pragma unroll
    for (int e = 0; e < 8; e++) { p[e] = expf(a[e] - m); s += p[e]; }
    float inv = 1.f / s;
    int i0 = 0; float v0 = a[0];
#pragma unroll
    for (int e = 1; e < 8; e++) if (a[e] > v0) { v0 = a[e]; i0 = e; }
    int i1 = -1; float v1 = -1e30f;
#pragma unroll
    for (int e = 0; e < 8; e++) if (e != i0 && a[e] > v1) { v1 = a[e]; i1 = e; }
    ge[t] = make_int2(i0, i1);
    gp[t] = make_float2(p[i0] * inv, p[i1] * inv);
  }
}

// ------- deterministic stable counting sort of 8192 pairs by expert (1 block) -------
// meta[0..8]=segment base; meta[9..16]=tileStart (BM=128), meta[17]=total128
__global__ void sort_kernel(const int2* __restrict__ ge, const float2* __restrict__ gp,
                            int* __restrict__ tok, float* __restrict__ ps,
                            int* __restrict__ meta) {
  __shared__ int hist[8], runn[8], wc[16][8], wb[16][8], baseS[9];
  int tid = threadIdx.x;
  int lane = tid & 63, wv = tid >> 6;
  if (tid < 8) hist[tid] = 0;
  __syncthreads();
  for (int i = tid; i < NPAIR; i += 1024) {
    int2 g = ge[i >> 1];
    int e = (i & 1) ? g.y : g.x;
    atomicAdd(&hist[e], 1);
  }
  __syncthreads();
  if (tid == 0) {
    int b = 0, ts1 = 0;
    for (int e = 0; e < 8; e++) {
      baseS[e] = b; meta[e] = b;
      meta[9 + e] = ts1;  ts1 += (hist[e] + 127) / 128;
      b += hist[e];
    }
    baseS[8] = b; meta[8] = b; meta[17] = ts1;
  }
  __syncthreads();
  if (tid < 8) runn[tid] = baseS[tid];
  __syncthreads();
  for (int c = 0; c < 8; c++) {
    int i = c * 1024 + tid;
    int2 g = ge[i >> 1];
    int e = (i & 1) ? g.y : g.x;
    int rank = 0;
#pragma unroll
    for (int ee = 0; ee < 8; ee++) {
      unsigned long long b = __ballot(e == ee);
      if (e == ee) rank = __popcll(b & ((1ull << lane) - 1ull));
      if (lane == 0) wc[wv][ee] = __popcll(b);
    }
    __syncthreads();
    if (tid < 8) {
      int s = runn[tid];
      for (int w = 0; w < 16; w++) { wb[w][tid] = s; s += wc[w][tid]; }
      runn[tid] = s;
    }
    __syncthreads();
    int pos = wb[wv][e] + rank;
    tok[pos] = i >> 1;
    float2 p2 = gp[i >> 1];
    ps[pos] = (i & 1) ? p2.y : p2.x;
    __syncthreads();
  }
}

// ---- grouped GEMM: BM=128, BN=128, BK=32, 256 thr (4 waves 2x2), 4 blocks/CU ----
// R13: the m97 loop — ZERO inline asm. Per K-tile: issue stage(kt+1) into the
// other buffer; ds_read frags(kt); 16 MFMA; __syncthreads(). The compiler
// emits fine-grained lgkmcnt between ds_read and MFMA and a single
// vmcnt(0)+lgkmcnt(0) drain at the barrier (stage loads get the whole MFMA
// cluster to land). No sched_barrier / setprio / asm waitcnt — R12's ablation
// + m141 showed those fences were the 2x loss.
// 2-buffer LDS (32 KiB), T2 swizzle via pre-swizzled source, XCD-chunked map.
// FIRST: A=xb[tok[row]], Bt=W1T -> h = relu(A*B + b1), bf16
// !FIRST: A=h[row],      Bt=W2T -> atomicAdd(out[tok[row]], (A*B + b2)*ps[row])
template <int KDIM, int NPE, bool FIRST, int NT>
__global__ __launch_bounds__(256, 4)
void moe_gemm_kernel(const bf16* __restrict__ A, const bf16* __restrict__ Bt,
                     const float* __restrict__ bias, const int* __restrict__ tok,
                     const float* __restrict__ ps, const int* __restrict__ meta,
                     bf16* __restrict__ hout, float* __restrict__ outp) {
  __shared__ bf16 lds[2][8192];  // per buffer: A 4096 elems (128x32), B 4096 (128x32)
  constexpr int nk = KDIM / 32;

  // runtime-balanced XCD-chunked mapping
  int MTa = meta[17];
  int xcd = blockIdx.x & 7;
  int idx = blockIdx.x >> 3;
  int mLo = (MTa * xcd) >> 3;
  int mHi = (MTa * (xcd + 1)) >> 3;
  int cnt = mHi - mLo;
  if (idx >= cnt * NT) return;
  int tileN = idx / cnt;
  int tileM = mLo + idx - tileN * cnt;

  int e = 0;
#pragma unroll
  for (int k = 1; k < 8; k++) if (tileM >= meta[9 + k]) e = k;
  int row0 = meta[e] + (tileM - meta[9 + e]) * 128;
  int segEnd = meta[e + 1];
  int n0 = tileN * 128;

  int t = threadIdx.x;
  // staging: round r -> LDS row r*64+(t>>2), dest 16B-chunk t&3 (linear dest);
  // pre-swizzle SOURCE chunk: c' = (t&3) ^ ((row>>1)&3) = (t&3) ^ ((t>>3)&3)
  const bf16* aSrc[2];
  const bf16* bSrc[2];
  {
    int swz = ((t & 3) ^ ((t >> 3) & 3)) * 8;
#pragma unroll
    for (int r = 0; r < 2; r++) {
      int row = r * 64 + (t >> 2);
      int gRow = row0 + row; if (gRow > NPAIR - 1) gRow = NPAIR - 1;
      int arow = FIRST ? tok[gRow] : gRow;
      aSrc[r] = A + (size_t)arow * KDIM + swz;
      bSrc[r] = Bt + ((size_t)e * NPE + n0 + row) * KDIM + swz;
    }
  }

  int lane = t & 63, wv = t >> 6;
  int wm = wv >> 1, wn = wv & 1;  // 2x2 waves; per-wave out 64x64
  int l15 = lane & 15, l4 = lane >> 4;
  int aOff[4], bOff[4];
#pragma unroll
  for (int m = 0; m < 4; m++) {
    int row = wm * 64 + m * 16 + l15;
    aOff[m] = row * 32 + ((l4 ^ ((row >> 1) & 3)) * 8);
  }
#pragma unroll
  for (int n = 0; n < 4; n++) {
    int row = wn * 64 + n * 16 + l15;
    bOff[n] = 4096 + row * 32 + ((l4 ^ ((row >> 1) & 3)) * 8);
  }

  f32x4 acc[4][4];
#pragma unroll
  for (int m = 0; m < 4; m++)
#pragma unroll
    for (int n = 0; n < 4; n++)
#pragma unroll
      for (int j = 0; j < 4; j++) acc[m][n][j] = 0.f;

  auto STAGE = [&](int kt, int buf) {
    bf16* sb = &lds[buf][0];
    int ko = kt * 32;
    gload16(aSrc[0] + ko, sb + t * 8);
    gload16(aSrc[1] + ko, sb + 2048 + t * 8);
    gload16(bSrc[0] + ko, sb + 4096 + t * 8);
    gload16(bSrc[1] + ko, sb + 6144 + t * 8);
  };

  STAGE(0, 0);
  __syncthreads();

  for (int kt = 0; kt < nk; kt++) {
    if (kt + 1 < nk) STAGE(kt + 1, (kt + 1) & 1);
    const bf16* sb = &lds[kt & 1][0];
    bf16x8 af[4], bfr[4];
#pragma unroll
    for (int m = 0; m < 4; m++) af[m] = *(const bf16x8*)(sb + aOff[m]);
#pragma unroll
    for (int n = 0; n < 4; n++) bfr[n] = *(const bf16x8*)(sb + bOff[n]);
#pragma unroll
    for (int m = 0; m < 4; m++)
#pragma unroll
      for (int n = 0; n < 4; n++)
        acc[m][n] = __builtin_amdgcn_mfma_f32_16x16x32_bf16(af[m], bfr[n], acc[m][n], 0, 0, 0);
    __syncthreads();  // drains stage(kt+1) (issued a full cluster ago) + frag reads
  }

  int colb = n0 + wn * 64 + l15;
  int rowb = wm * 64 + l4 * 4;
  float bia[4];
#pragma unroll
  for (int n = 0; n < 4; n++) bia[n] = bias[(size_t)e * NPE + colb + n * 16];
#pragma unroll
  for (int m = 0; m < 4; m++) {
#pragma unroll
    for (int jj = 0; jj < 4; jj++) {
      int gRow = row0 + rowb + m * 16 + jj;
      if (gRow < segEnd) {
        if (FIRST) {
#pragma unroll
          for (int n = 0; n < 4; n++) {
            float v = acc[m][n][jj] + bia[n];
            v = fmaxf(v, 0.f);
            hout[(size_t)gRow * NPE + colb + n * 16] = (bf16)v;
          }
        } else {
          float pscale = ps[gRow];
          float* orow = outp + (size_t)tok[gRow] * DDIM;
#pragma unroll
          for (int n = 0; n < 4; n++) {
            float v = (acc[m][n][jj] + bia[n]) * pscale;
            atomicAdd(orow + colb + n * 16, v);  // exactly 2 adds/elem -> deterministic
          }
        }
      }
    }
  }
}

extern "C" void kernel_launch(void* const* d_in, const int* in_sizes, int n_in,
                              void* d_out, int out_size, void* d_ws, size_t ws_size,
                              hipStream_t stream) {
  (void)in_sizes; (void)n_in; (void)out_size; (void)ws_size;
  const float* x  = (const float*)d_in[0];
  const float* Wg = (const float*)d_in[1];
  const float* W1 = (const float*)d_in[2];
  const float* b1 = (const float*)d_in[3];
  const float* W2 = (const float*)d_in[4];
  const float* b2 = (const float*)d_in[5];
  float* out = (float*)d_out;

  char* ws = (char*)d_ws;
  bf16*  xb   = (bf16*)(ws);                     //   8 MiB: [4096][1024] bf16
  bf16*  W1T  = (bf16*)(ws + (8ull  << 20));     //  32 MiB: [8][2048][1024] bf16
  bf16*  W2T  = (bf16*)(ws + (40ull << 20));     //  32 MiB: [8][1024][2048] bf16
  bf16*  hbuf = (bf16*)(ws + (72ull << 20));     //  32 MiB: [8192][2048] bf16
  char*  ext  = ws + (104ull << 20);
  int2*   ge      = (int2*)(ext);
  float2* gp      = (float2*)(ext + (64u  << 10));
  int*    tok     = (int*)(ext + (128u << 10));
  float*  psarr   = (float*)(ext + (160u << 10));
  int*    meta    = (int*)(ext + (224u << 10));

  transpose_cvt_kernel<<<dim3(64, 32, 8), 256, 0, stream>>>(W1, W1T, 1024, 2048);
  transpose_cvt_kernel<<<dim3(32, 64, 8), 256, 0, stream>>>(W2, W2T, 2048, 1024);
  gate_kernel<<<1024, 256, 0, stream>>>(x, Wg, ge, gp, xb, out);
  sort_kernel<<<1, 1024, 0, stream>>>(ge, gp, tok, psarr, meta);
  // per-XCD M-slots = ceil(71/8) = 9
  // G1: NT=16 (HDIM/128) -> grid 9*16*8 = 1152
  moe_gemm_kernel<1024, 2048, true, 16><<<dim3(1152), 256, 0, stream>>>(
      xb, W1T, b1, tok, psarr, meta, hbuf, nullptr);
  // G2: NT=8 (DDIM/128) -> grid 9*8*8 = 576
  moe_gemm_kernel<2048, 1024, false, 8><<<dim3(576), 256, 0, stream>>>(
      hbuf, W2T, b2, tok, psarr, meta, nullptr, out);
}